// Round 5
// baseline (7695.694 us; speedup 1.0000x reference)
//
#include <hip/hip_runtime.h>
#include <stdint.h>

typedef _Float16 f16;
typedef _Float16 f16x8 __attribute__((ext_vector_type(8)));
typedef float f32x4 __attribute__((ext_vector_type(4)));

#define NBATCH 64

__device__ __forceinline__ float sigmoidf_(float x) {
    return 1.0f / (1.0f + __expf(-x));
}
__device__ __forceinline__ float tanh_(float x) {
    x = fminf(fmaxf(x, -15.0f), 15.0f);
    float e = __expf(2.0f * x);
    return (e - 1.0f) / (e + 1.0f);
}

// LDS-only barrier: orders ds ops across the block WITHOUT draining vmcnt
// (unlike __syncthreads, which emits s_waitcnt vmcnt(0) before s_barrier).
// Used only where the communicated data is purely in LDS.
__device__ __forceinline__ void lds_barrier() {
    asm volatile("s_waitcnt lgkmcnt(0)" ::: "memory");
    __builtin_amdgcn_s_barrier();
    asm volatile("" ::: "memory");
}

// ---------------- fold LoRA into dense weight: dst = fp16(W + 2*B@A) --------
__global__ __launch_bounds__(256) void fold_lora(
    const float* __restrict__ W, const float* __restrict__ Bm,
    const float* __restrict__ Am, f16* __restrict__ dst, int K) {
    int cid = blockIdx.x * 256 + threadIdx.x;
    int kc = K >> 3;
    int r = cid / kc;
    int k0 = (cid - r * kc) * 8;
    float bb[8];
#pragma unroll
    for (int j = 0; j < 8; j++) bb[j] = Bm[r * 8 + j];
#pragma unroll
    for (int i = 0; i < 8; i++) {
        float s = 0.0f;
#pragma unroll
        for (int j = 0; j < 8; j++) s += bb[j] * Am[j * K + k0 + i];
        float v = W[(size_t)r * K + k0 + i] + 2.0f * s;
        dst[(size_t)r * K + k0 + i] = (f16)v;
    }
}

// ---------------- bias sums + flag/cstate zeroing ----------------------------
__global__ __launch_bounds__(256) void init_misc(
    const float* __restrict__ bih0, const float* __restrict__ bhh0,
    const float* __restrict__ bih1, const float* __restrict__ bhh1,
    float* __restrict__ bsum0, float* __restrict__ bsum1,
    int* __restrict__ flags0, int* __restrict__ flags1,
    float* __restrict__ c0, float* __restrict__ c1) {
    int i = blockIdx.x * 256 + threadIdx.x;
    if (i < 4096) {
        bsum0[i] = bih0[i] + bhh0[i];
        bsum1[i] = bih1[i] + bhh1[i];
    }
    if (i < 256) { flags0[i] = 0; flags1[i] = 0; }
    c0[i] = 0.0f;
    c1[i] = 0.0f;
}

// ---------------- embedding gather chunk -> fp16 seqc [CH][B][512] -----------
__global__ __launch_bounds__(256) void embed_gather(
    const int* __restrict__ x, const float* __restrict__ emb,
    f16* __restrict__ seqc, int t0) {
    int lt = blockIdx.x;
    int t = t0 + lt;
#pragma unroll
    for (int c = 0; c < 16; c++) {
        int lin = c * 256 + threadIdx.x;
        int b = lin >> 6;
        int e0 = (lin & 63) * 8;
        int tok = x[b * 512 + t];
        const float* src = emb + (size_t)tok * 512 + e0;
        f16x8 v;
#pragma unroll
        for (int i = 0; i < 8; i++) v[i] = (f16)src[i];
        *(f16x8*)&seqc[((size_t)lt * 64 + b) * 512 + e0] = v;
    }
}

// ---------------- NT GEMM: C = A[M][K] @ Bw[4096][K]^T -----------------------
// C stored gate-interleaved: C[m][u*4+gate] where n = gate*1024+u.
// tile 128x128, block 256 threads, grid mtiles*32 (mt = bid & mtmask).
__global__ __launch_bounds__(256) void gemm_nt(
    const f16* __restrict__ A, const f16* __restrict__ Bw,
    float* __restrict__ C, int K, int mtmask, int mtshift) {
    __shared__ f16 As[128 * 40];
    __shared__ f16 Bs[128 * 40];
    int bid = blockIdx.x;
    int mt = bid & mtmask, nt = bid >> mtshift;
    int tid = threadIdx.x;
    int w = tid >> 6, lane = tid & 63;
    int lm = lane & 15, lq = lane >> 4;
    int wm = (w >> 1) * 64, wn = (w & 1) * 64;
    f32x4 acc[4][4];
#pragma unroll
    for (int i = 0; i < 4; i++)
#pragma unroll
        for (int j = 0; j < 4; j++) acc[i][j] = f32x4{0.f, 0.f, 0.f, 0.f};
    const f16* Ab = A + (size_t)mt * 128 * K;
    const f16* Bb = Bw + (size_t)nt * 128 * K;
    int nkc = K >> 5;
    for (int kc = 0; kc < nkc; kc++) {
#pragma unroll
        for (int i = 0; i < 2; i++) {
            int cid = tid + i * 256;
            int r = cid >> 2, c8 = (cid & 3) * 8;
            *(f16x8*)&As[r * 40 + c8] = *(const f16x8*)&Ab[(size_t)r * K + kc * 32 + c8];
            *(f16x8*)&Bs[r * 40 + c8] = *(const f16x8*)&Bb[(size_t)r * K + kc * 32 + c8];
        }
        __syncthreads();
        f16x8 af[4], bf[4];
#pragma unroll
        for (int mi = 0; mi < 4; mi++)
            af[mi] = *(const f16x8*)&As[(wm + mi * 16 + lm) * 40 + lq * 8];
#pragma unroll
        for (int ni = 0; ni < 4; ni++)
            bf[ni] = *(const f16x8*)&Bs[(wn + ni * 16 + lm) * 40 + lq * 8];
#pragma unroll
        for (int mi = 0; mi < 4; mi++)
#pragma unroll
            for (int ni = 0; ni < 4; ni++)
                acc[mi][ni] = __builtin_amdgcn_mfma_f32_16x16x32_f16(
                    af[mi], bf[ni], acc[mi][ni], 0, 0, 0);
        __syncthreads();
    }
#pragma unroll
    for (int mi = 0; mi < 4; mi++)
#pragma unroll
        for (int ni = 0; ni < 4; ni++)
#pragma unroll
            for (int r = 0; r < 4; r++) {
                int m = mt * 128 + wm + mi * 16 + lq * 4 + r;
                int n = nt * 128 + wn + ni * 16 + lm;
                int gate = n >> 10, u = n & 1023;
                C[(size_t)m * 4096 + u * 4 + gate] = acc[mi][ni][r];
            }
}

// ---------------- fused 2-layer persistent recurrence ------------------------
// Round-2 joint schedule (poll together, stage together) with a slimmed sync
// skeleton per step:
//   poll(1) / syncthreads / stage A+B / syncthreads /
//   phaseA: mfma, xch, lds_barrier, gates, issue hA store (NO drain) /
//   lds_barrier (xch reuse) /
//   phaseB: mfma, xch, lds_barrier, gates, issue hB store /
//   syncthreads (single vmcnt drain for both publishes) / flag store(1)
// vs round-2's 6 full-drain barriers + 2 polls + 2 flag stores. The A and B
// flag rounds merge into ONE flags array counting fused steps (fbase+lt+1),
// stored only after the end-of-step drain certifies both h publishes at the
// MALL. Ring-safety invariant unchanged: a writer of slot s has passed a poll
// proving every reader of s's previous occupant completed its step.

__device__ __forceinline__ void stage_h(f16* hbuf, const uint32_t* hx, int slot,
                                        int bg, int tid) {
    const uint64_t* hp = (const uint64_t*)hx + (size_t)slot * (NBATCH * 256);
#pragma unroll
    for (int i = 0; i < 16; i++) {
        int lin = tid + i * 256;          // [0,4096) 8B granules
        int b = lin >> 8, d = lin & 255;
        uint64_t v = __hip_atomic_load(hp + (size_t)(bg * 16 + b) * 256 + d,
                                       __ATOMIC_RELAXED, __HIP_MEMORY_SCOPE_AGENT);
        *(uint64_t*)((char*)hbuf + (size_t)b * 2064 + (size_t)d * 8) = v;
    }
}

__device__ __forceinline__ f32x4 recur_mfma(const f16* hb, const f16x8* wf) {
    f32x4 a0 = f32x4{0.f, 0.f, 0.f, 0.f};
    f32x4 a1 = f32x4{0.f, 0.f, 0.f, 0.f};
    f32x4 a2 = f32x4{0.f, 0.f, 0.f, 0.f};
    f32x4 a3 = f32x4{0.f, 0.f, 0.f, 0.f};
#pragma unroll
    for (int kk = 0; kk < 32; kk += 4) {
        a0 = __builtin_amdgcn_mfma_f32_16x16x32_f16(*(const f16x8*)(hb + (kk + 0) * 32), wf[kk + 0], a0, 0, 0, 0);
        a1 = __builtin_amdgcn_mfma_f32_16x16x32_f16(*(const f16x8*)(hb + (kk + 1) * 32), wf[kk + 1], a1, 0, 0, 0);
        a2 = __builtin_amdgcn_mfma_f32_16x16x32_f16(*(const f16x8*)(hb + (kk + 2) * 32), wf[kk + 2], a2, 0, 0, 0);
        a3 = __builtin_amdgcn_mfma_f32_16x16x32_f16(*(const f16x8*)(hb + (kk + 3) * 32), wf[kk + 3], a3, 0, 0, 0);
    }
    return (a0 + a1) + (a2 + a3);
}

__global__ __launch_bounds__(256, 1) void lstm_recur2(
    const float* __restrict__ xpA, const f16* __restrict__ WhA,
    const float* __restrict__ bsA, uint32_t* __restrict__ hxA,
    float* __restrict__ cstA, int t0a, int smaskA,
    const float* __restrict__ xpB, const f16* __restrict__ WhB,
    const float* __restrict__ bsB, uint32_t* __restrict__ hxB,
    float* __restrict__ cstB, int t0b,
    int* __restrict__ flags, int fbase,
    const int* __restrict__ lengths, float* __restrict__ dout, int nsteps) {
    __shared__ f16 hbufA[16 * 1032];
    __shared__ f16 hbufB[16 * 1032];
    __shared__ float xch[4 * 16 * 16];
    const int tid = threadIdx.x;
    const int g = tid >> 6, lane = tid & 63;
    const int lm = lane & 15, lq = lane >> 4;
    const int bid = blockIdx.x;
    const int bg = bid >> 6, jg = bid & 63;
    const bool hasA = (t0a >= 0), hasB = (t0b >= 0);

    // W fragments resident for the whole dispatch (both layers)
    f16x8 wfA[32], wfB[32];
    {
        const int grow = g * 1024 + jg * 16 + lm;
        if (hasA) {
            const f16* wp = WhA + (size_t)grow * 1024 + lq * 8;
#pragma unroll
            for (int kk = 0; kk < 32; kk++) wfA[kk] = *(const f16x8*)(wp + kk * 32);
        }
        if (hasB) {
            const f16* wp = WhB + (size_t)grow * 1024 + lq * 8;
#pragma unroll
            for (int kk = 0; kk < 32; kk++) wfB[kk] = *(const f16x8*)(wp + kk * 32);
        }
    }
    const int eb = tid >> 4, eu = tid & 15;
    const int batch = bg * 16 + eb;
    const int hidx = jg * 16 + eu;
    float biasA[4], biasB[4];
#pragma unroll
    for (int g2 = 0; g2 < 4; g2++) {
        biasA[g2] = hasA ? bsA[g2 * 1024 + hidx] : 0.0f;
        biasB[g2] = hasB ? bsB[g2 * 1024 + hidx] : 0.0f;
    }
    const int mylen = lengths[batch];
    float cA = (hasA && t0a > 0) ? cstA[(size_t)batch * 1024 + hidx] : 0.0f;
    float cB = (hasB && t0b > 0) ? cstB[(size_t)batch * 1024 + hidx] : 0.0f;
    const int myflag = bg * 64 + jg;
    const int* fl = flags + bg * 64;

    for (int lt = 0; lt < nsteps; lt++) {
        const int ta = t0a + lt, tb = t0b + lt;
        const bool doA = hasA && ta > 0;
        const bool doB = hasB && tb > 0;
        // prefetch xp rows (recurrence-independent; hides under flag wait)
        f32x4 xvA = f32x4{0.f, 0.f, 0.f, 0.f};
        f32x4 xvB = f32x4{0.f, 0.f, 0.f, 0.f};
        if (hasA)
            xvA = *(const f32x4*)(xpA + ((size_t)lt * 64 + batch) * 4096 + (hidx << 2));
        if (hasB)
            xvB = *(const f32x4*)(xpB + ((size_t)lt * 64 + batch) * 4096 + (hidx << 2));
        // single merged poll: all bg-group blocks completed fused step lt-1
        if (tid < 64) {
            for (;;) {
                int v = __hip_atomic_load(fl + tid, __ATOMIC_RELAXED,
                                          __HIP_MEMORY_SCOPE_AGENT);
                if (__all(v >= fbase + lt)) break;
                __builtin_amdgcn_s_sleep(1);
            }
        }
        __syncthreads();
        // stage both h slices; the two load streams overlap in flight
        if (doA) stage_h(hbufA, hxA, (ta - 1) & smaskA, bg, tid);
        if (doB) stage_h(hbufB, hxB, (tb - 1) & 1, bg, tid);
        __syncthreads();

        // ---------------- phase A: layer 0, step ta ----------------
        if (hasA) {
            f32x4 pre = f32x4{0.f, 0.f, 0.f, 0.f};
            if (doA) pre = recur_mfma(&hbufA[lm * 1032 + lq * 8], wfA);
#pragma unroll
            for (int r = 0; r < 4; r++)
                xch[(g * 16 + lq * 4 + r) * 16 + lm] = pre[r];
            lds_barrier();
            float pg[4];
#pragma unroll
            for (int g2 = 0; g2 < 4; g2++)
                pg[g2] = xch[(g2 * 16 + eb) * 16 + eu] + xvA[g2] + biasA[g2];
            cA = sigmoidf_(pg[1]) * cA + sigmoidf_(pg[0]) * tanh_(pg[2]);
            float h = sigmoidf_(pg[3]) * tanh_(cA);
            float hn = __shfl_xor(h, 1);
            if ((tid & 1) == 0) {
                f16 a = (f16)h, b2 = (f16)hn;
                uint16_t lo = *(uint16_t*)&a, hi = *(uint16_t*)&b2;
                uint32_t pk = (uint32_t)lo | ((uint32_t)hi << 16);
                // store stays in flight through phase B; drained at end-of-step
                __hip_atomic_store(hxA + (size_t)(ta & smaskA) * (NBATCH * 512)
                                       + (size_t)batch * 512 + (hidx >> 1),
                                   pk, __ATOMIC_RELAXED, __HIP_MEMORY_SCOPE_AGENT);
            }
            lds_barrier();  // xch reads retired before phase B overwrites
        }
        // ---------------- phase B: layer 1, step tb ----------------
        if (hasB) {
            f32x4 pre = f32x4{0.f, 0.f, 0.f, 0.f};
            if (doB) pre = recur_mfma(&hbufB[lm * 1032 + lq * 8], wfB);
#pragma unroll
            for (int r = 0; r < 4; r++)
                xch[(g * 16 + lq * 4 + r) * 16 + lm] = pre[r];
            lds_barrier();
            float pg[4];
#pragma unroll
            for (int g2 = 0; g2 < 4; g2++)
                pg[g2] = xch[(g2 * 16 + eb) * 16 + eu] + xvB[g2] + biasB[g2];
            cB = sigmoidf_(pg[1]) * cB + sigmoidf_(pg[0]) * tanh_(pg[2]);
            float h = sigmoidf_(pg[3]) * tanh_(cB);
            float hn = __shfl_xor(h, 1);
            if ((tid & 1) == 0) {
                f16 a = (f16)h, b2 = (f16)hn;
                uint16_t lo = *(uint16_t*)&a, hi = *(uint16_t*)&b2;
                uint32_t pk = (uint32_t)lo | ((uint32_t)hi << 16);
                __hip_atomic_store(hxB + (size_t)(tb & 1) * (NBATCH * 512)
                                       + (size_t)batch * 512 + (hidx >> 1),
                                   pk, __ATOMIC_RELAXED, __HIP_MEMORY_SCOPE_AGENT);
            }
            if (dout != nullptr && tb == mylen - 1)
                dout[(size_t)batch * 1024 + hidx] = h;
        }
        __syncthreads();  // single vmcnt(0) drain: hA and hB publishes at MALL
        if (tid == 0)
            __hip_atomic_store(flags + myflag, fbase + lt + 1, __ATOMIC_RELAXED,
                               __HIP_MEMORY_SCOPE_AGENT);
    }
    if (hasA) cstA[(size_t)batch * 1024 + hidx] = cA;
    if (hasB) cstB[(size_t)batch * 1024 + hidx] = cB;
}

extern "C" void kernel_launch(void* const* d_in, const int* in_sizes, int n_in,
                              void* d_out, int out_size, void* d_ws, size_t ws_size,
                              hipStream_t stream) {
    const int*   x     = (const int*)d_in[0];
    const int*   len   = (const int*)d_in[1];
    const float* emb   = (const float*)d_in[2];
    const float* W_ih0 = (const float*)d_in[3];
    const float* b_ih0 = (const float*)d_in[4];
    const float* A_ih0 = (const float*)d_in[5];
    const float* B_ih0 = (const float*)d_in[6];
    const float* W_hh0 = (const float*)d_in[7];
    const float* b_hh0 = (const float*)d_in[8];
    const float* A_hh0 = (const float*)d_in[9];
    const float* B_hh0 = (const float*)d_in[10];
    const float* W_ih1 = (const float*)d_in[11];
    const float* b_ih1 = (const float*)d_in[12];
    const float* A_ih1 = (const float*)d_in[13];
    const float* B_ih1 = (const float*)d_in[14];
    const float* W_hh1 = (const float*)d_in[15];
    const float* b_hh1 = (const float*)d_in[16];
    const float* A_hh1 = (const float*)d_in[17];
    const float* B_hh1 = (const float*)d_in[18];

    char* ws = (char*)d_ws;
    size_t off = 0;
    auto alloc = [&](size_t bytes) {
        size_t o = off;
        off += (bytes + 255) & ~(size_t)255;
        return o;
    };
    f16*   W0f    = (f16*)(ws + alloc((size_t)4096 * 512 * 2));
    f16*   Wh0f   = (f16*)(ws + alloc((size_t)4096 * 1024 * 2));
    f16*   W1f    = (f16*)(ws + alloc((size_t)4096 * 1024 * 2));
    f16*   Wh1f   = (f16*)(ws + alloc((size_t)4096 * 1024 * 2));
    float* bsum0  = (float*)(ws + alloc(4096 * 4));
    float* bsum1  = (float*)(ws + alloc(4096 * 4));
    int*   flags0 = (int*)(ws + alloc(4096));
    int*   flags1 = (int*)(ws + alloc(4096));
    float* c0st   = (float*)(ws + alloc((size_t)64 * 1024 * 4));
    float* c1st   = (float*)(ws + alloc((size_t)64 * 1024 * 4));
    f16*   hx1    = (f16*)(ws + alloc((size_t)2 * 64 * 1024 * 2));

    // runtime chunk length: prefer 64 (fewer dispatches), fall back to 32
    // if the workspace can't hold two CH*64*4096 f32 xp buffers.
    int CHv = 64;
    {
        auto al = [](size_t b) { return (b + 255) & ~(size_t)255; };
        size_t need = off
            + al((size_t)64 * 64 * 512 * 2)        // seqc
            + al((size_t)64 * 64 * 1024 * 2)       // h0 ring
            + 2 * al((size_t)64 * 64 * 4096 * 4);  // xp0c, xp1c
        if (ws_size < need) CHv = 32;
    }
    const int NCHv = 512 / CHv;
    f16*   seqc = (f16*)(ws + alloc((size_t)CHv * 64 * 512 * 2));
    f16*   h0c  = (f16*)(ws + alloc((size_t)CHv * 64 * 1024 * 2));
    float* xp0c = (float*)(ws + alloc((size_t)CHv * 64 * 4096 * 4));
    float* xp1c = (float*)(ws + alloc((size_t)CHv * 64 * 4096 * 4));
    const int mtiles  = (CHv * 64) / 128;       // 32 or 16
    const int mtmask  = mtiles - 1;
    const int mtshift = (CHv == 64) ? 5 : 4;
    (void)in_sizes; (void)n_in; (void)out_size;

    fold_lora<<<1024, 256, 0, stream>>>(W_ih0, B_ih0, A_ih0, W0f, 512);
    fold_lora<<<2048, 256, 0, stream>>>(W_hh0, B_hh0, A_hh0, Wh0f, 1024);
    fold_lora<<<2048, 256, 0, stream>>>(W_ih1, B_ih1, A_ih1, W1f, 1024);
    fold_lora<<<2048, 256, 0, stream>>>(W_hh1, B_hh1, A_hh1, Wh1f, 1024);
    init_misc<<<256, 256, 0, stream>>>(b_ih0, b_hh0, b_ih1, b_hh1,
                                       bsum0, bsum1, flags0, flags1, c0st, c1st);

    // Software pipeline at dispatch level: fused(c) runs layer-0 chunk c and
    // layer-1 chunk c-1 concurrently; gemm1(c-1) consumes h0c (written by
    // fused(c-1)) before fused(c) overwrites it (stream order).
    for (int c = 0; c <= NCHv; c++) {
        if (c < NCHv) {
            embed_gather<<<CHv, 256, 0, stream>>>(x, emb, seqc, c * CHv);
            gemm_nt<<<mtiles * 32, 256, 0, stream>>>(seqc, W0f, xp0c, 512,
                                                     mtmask, mtshift);
        }
        if (c > 0)
            gemm_nt<<<mtiles * 32, 256, 0, stream>>>(h0c, W1f, xp1c, 1024,
                                                     mtmask, mtshift);
        lstm_recur2<<<256, 256, 0, stream>>>(
            xp0c, Wh0f, bsum0, (uint32_t*)h0c, c0st,
            (c < NCHv) ? c * CHv : -1, CHv - 1,
            xp1c, Wh1f, bsum1, (uint32_t*)hx1, c1st,
            (c > 0) ? (c - 1) * CHv : -1,
            flags0, c * CHv,
            len, (float*)d_out, CHv);
    }
}

// Round 6
// 6008.542 us; speedup vs baseline: 1.2808x; 1.2808x over previous
//
#include <hip/hip_runtime.h>
#include <stdint.h>

typedef _Float16 f16;
typedef _Float16 f16x8 __attribute__((ext_vector_type(8)));
typedef float f32x4 __attribute__((ext_vector_type(4)));

#define NBATCH 64

__device__ __forceinline__ float sigmoidf_(float x) {
    return 1.0f / (1.0f + __expf(-x));
}
__device__ __forceinline__ float tanh_(float x) {
    x = fminf(fmaxf(x, -15.0f), 15.0f);
    float e = __expf(2.0f * x);
    return (e - 1.0f) / (e + 1.0f);
}

// ---------------- fold LoRA into dense weight: dst = fp16(W + 2*B@A) --------
__global__ __launch_bounds__(256) void fold_lora(
    const float* __restrict__ W, const float* __restrict__ Bm,
    const float* __restrict__ Am, f16* __restrict__ dst, int K) {
    int cid = blockIdx.x * 256 + threadIdx.x;
    int kc = K >> 3;
    int r = cid / kc;
    int k0 = (cid - r * kc) * 8;
    float bb[8];
#pragma unroll
    for (int j = 0; j < 8; j++) bb[j] = Bm[r * 8 + j];
#pragma unroll
    for (int i = 0; i < 8; i++) {
        float s = 0.0f;
#pragma unroll
        for (int j = 0; j < 8; j++) s += bb[j] * Am[j * K + k0 + i];
        float v = W[(size_t)r * K + k0 + i] + 2.0f * s;
        dst[(size_t)r * K + k0 + i] = (f16)v;
    }
}

// ---------------- bias sums + flag/cstate zeroing ----------------------------
__global__ __launch_bounds__(256) void init_misc(
    const float* __restrict__ bih0, const float* __restrict__ bhh0,
    const float* __restrict__ bih1, const float* __restrict__ bhh1,
    float* __restrict__ bsum0, float* __restrict__ bsum1,
    int* __restrict__ flags0, int* __restrict__ flags1,
    float* __restrict__ c0, float* __restrict__ c1) {
    int i = blockIdx.x * 256 + threadIdx.x;
    if (i < 4096) {
        bsum0[i] = bih0[i] + bhh0[i];
        bsum1[i] = bih1[i] + bhh1[i];
    }
    if (i < 256) { flags0[i] = 0; flags1[i] = 0; }
    c0[i] = 0.0f;
    c1[i] = 0.0f;
}

// ---------------- embedding gather chunk -> fp16 seqc [CH][B][512] -----------
__global__ __launch_bounds__(256) void embed_gather(
    const int* __restrict__ x, const float* __restrict__ emb,
    f16* __restrict__ seqc, int t0) {
    int lt = blockIdx.x;
    int t = t0 + lt;
#pragma unroll
    for (int c = 0; c < 16; c++) {
        int lin = c * 256 + threadIdx.x;
        int b = lin >> 6;
        int e0 = (lin & 63) * 8;
        int tok = x[b * 512 + t];
        const float* src = emb + (size_t)tok * 512 + e0;
        f16x8 v;
#pragma unroll
        for (int i = 0; i < 8; i++) v[i] = (f16)src[i];
        *(f16x8*)&seqc[((size_t)lt * 64 + b) * 512 + e0] = v;
    }
}

// ---------------- NT GEMM: C = A[M][K] @ Bw[4096][K]^T -----------------------
// C stored gate-interleaved: C[m][u*4+gate] where n = gate*1024+u.
// tile 128x128, block 256 threads, grid mtiles*32 (mt = bid & mtmask).
__global__ __launch_bounds__(256) void gemm_nt(
    const f16* __restrict__ A, const f16* __restrict__ Bw,
    float* __restrict__ C, int K, int mtmask, int mtshift) {
    __shared__ f16 As[128 * 40];
    __shared__ f16 Bs[128 * 40];
    int bid = blockIdx.x;
    int mt = bid & mtmask, nt = bid >> mtshift;
    int tid = threadIdx.x;
    int w = tid >> 6, lane = tid & 63;
    int lm = lane & 15, lq = lane >> 4;
    int wm = (w >> 1) * 64, wn = (w & 1) * 64;
    f32x4 acc[4][4];
#pragma unroll
    for (int i = 0; i < 4; i++)
#pragma unroll
        for (int j = 0; j < 4; j++) acc[i][j] = f32x4{0.f, 0.f, 0.f, 0.f};
    const f16* Ab = A + (size_t)mt * 128 * K;
    const f16* Bb = Bw + (size_t)nt * 128 * K;
    int nkc = K >> 5;
    for (int kc = 0; kc < nkc; kc++) {
#pragma unroll
        for (int i = 0; i < 2; i++) {
            int cid = tid + i * 256;
            int r = cid >> 2, c8 = (cid & 3) * 8;
            *(f16x8*)&As[r * 40 + c8] = *(const f16x8*)&Ab[(size_t)r * K + kc * 32 + c8];
            *(f16x8*)&Bs[r * 40 + c8] = *(const f16x8*)&Bb[(size_t)r * K + kc * 32 + c8];
        }
        __syncthreads();
        f16x8 af[4], bf[4];
#pragma unroll
        for (int mi = 0; mi < 4; mi++)
            af[mi] = *(const f16x8*)&As[(wm + mi * 16 + lm) * 40 + lq * 8];
#pragma unroll
        for (int ni = 0; ni < 4; ni++)
            bf[ni] = *(const f16x8*)&Bs[(wn + ni * 16 + lm) * 40 + lq * 8];
#pragma unroll
        for (int mi = 0; mi < 4; mi++)
#pragma unroll
            for (int ni = 0; ni < 4; ni++)
                acc[mi][ni] = __builtin_amdgcn_mfma_f32_16x16x32_f16(
                    af[mi], bf[ni], acc[mi][ni], 0, 0, 0);
        __syncthreads();
    }
#pragma unroll
    for (int mi = 0; mi < 4; mi++)
#pragma unroll
        for (int ni = 0; ni < 4; ni++)
#pragma unroll
            for (int r = 0; r < 4; r++) {
                int m = mt * 128 + wm + mi * 16 + lq * 4 + r;
                int n = nt * 128 + wn + ni * 16 + lm;
                int gate = n >> 10, u = n & 1023;
                C[(size_t)m * 4096 + u * 4 + gate] = acc[mi][ni][r];
            }
}

// ---------------- dual-chain persistent recurrence ---------------------------
// Blocks 0..255 run layer-0 chunk c; blocks 256..511 run layer-1 chunk c-1,
// CONCURRENTLY on disjoint CUs (2 blocks/CU: LDS 37376*2 <= 160K, VGPR ~100
// <= 128 -> residency guaranteed; __launch_bounds__(256,2)). The two chains
// share NOTHING inside a dispatch (separate xp, rings, flags, cstate), so the
// slot period is ONE chain's step (~7 us) instead of phaseA+phaseB (11.1 us,
// round-2). Loop body is the verified round-0 single-layer kernel verbatim.

__device__ __forceinline__ void stage_h(f16* hbuf, const uint32_t* hx, int slot,
                                        int bg, int tid) {
    const uint64_t* hp = (const uint64_t*)hx + (size_t)slot * (NBATCH * 256);
#pragma unroll
    for (int i = 0; i < 16; i++) {
        int lin = tid + i * 256;          // [0,4096) 8B granules
        int b = lin >> 8, d = lin & 255;
        uint64_t v = __hip_atomic_load(hp + (size_t)(bg * 16 + b) * 256 + d,
                                       __ATOMIC_RELAXED, __HIP_MEMORY_SCOPE_AGENT);
        *(uint64_t*)((char*)hbuf + (size_t)b * 2064 + (size_t)d * 8) = v;
    }
}

__device__ __forceinline__ f32x4 recur_mfma(const f16* hb, const f16x8* wf) {
    f32x4 a0 = f32x4{0.f, 0.f, 0.f, 0.f};
    f32x4 a1 = f32x4{0.f, 0.f, 0.f, 0.f};
    f32x4 a2 = f32x4{0.f, 0.f, 0.f, 0.f};
    f32x4 a3 = f32x4{0.f, 0.f, 0.f, 0.f};
#pragma unroll
    for (int kk = 0; kk < 32; kk += 4) {
        a0 = __builtin_amdgcn_mfma_f32_16x16x32_f16(*(const f16x8*)(hb + (kk + 0) * 32), wf[kk + 0], a0, 0, 0, 0);
        a1 = __builtin_amdgcn_mfma_f32_16x16x32_f16(*(const f16x8*)(hb + (kk + 1) * 32), wf[kk + 1], a1, 0, 0, 0);
        a2 = __builtin_amdgcn_mfma_f32_16x16x32_f16(*(const f16x8*)(hb + (kk + 2) * 32), wf[kk + 2], a2, 0, 0, 0);
        a3 = __builtin_amdgcn_mfma_f32_16x16x32_f16(*(const f16x8*)(hb + (kk + 3) * 32), wf[kk + 3], a3, 0, 0, 0);
    }
    return (a0 + a1) + (a2 + a3);
}

// verified round-0 single-layer recurrence loop, parameterized by logical bid
__device__ __forceinline__ void chain_loop(
    const float* __restrict__ xp, const f16* __restrict__ Wh,
    const float* __restrict__ bsum, uint32_t* __restrict__ hexch,
    int* __restrict__ flags, float* __restrict__ cstate,
    int t0, int smask, const int* __restrict__ lengths,
    float* __restrict__ dout, int bid, int nsteps,
    f16* hbuf, float* xch) {
    int tid = threadIdx.x;
    int g = tid >> 6, lane = tid & 63;
    int lm = lane & 15, lq = lane >> 4;
    int bg = bid >> 6, jg = bid & 63;

    // W fragments resident in registers for all steps
    f16x8 wfrag[32];
    {
        int grow = g * 1024 + jg * 16 + lm;
        const f16* wp = Wh + (size_t)grow * 1024 + lq * 8;
#pragma unroll
        for (int kk = 0; kk < 32; kk++) wfrag[kk] = *(const f16x8*)(wp + kk * 32);
    }
    int eb = tid >> 4, eu = tid & 15;
    int batch = bg * 16 + eb;
    int hidx = jg * 16 + eu;
    float bias[4];
#pragma unroll
    for (int g2 = 0; g2 < 4; g2++) bias[g2] = bsum[g2 * 1024 + hidx];
    int mylen = (lengths != nullptr) ? lengths[batch] : -1;
    float c = (t0 > 0) ? cstate[(size_t)batch * 1024 + hidx] : 0.0f;
    const int myflag = bg * 64 + jg;

    for (int lt = 0; lt < nsteps; lt++) {
        int t = t0 + lt;
        // prefetch xp (recurrence-independent): latency hides under flag wait
        const f32x4 xpv = *(const f32x4*)(xp + ((size_t)lt * 64 + batch) * 4096 + (hidx << 2));
        f32x4 pre = f32x4{0.f, 0.f, 0.f, 0.f};
        if (t > 0) {
            if (tid < 64) {
                const int* fl = flags + bg * 64;
                for (;;) {
                    int v = __hip_atomic_load(fl + tid, __ATOMIC_RELAXED,
                                              __HIP_MEMORY_SCOPE_AGENT);
                    if (__all(v >= t)) break;
                    __builtin_amdgcn_s_sleep(1);
                }
            }
            __syncthreads();
            stage_h(hbuf, hexch, (t - 1) & smask, bg, tid);
            __syncthreads();
            pre = recur_mfma(&hbuf[lm * 1032 + lq * 8], wfrag);
        }
        // cross-wave exchange: D element (m=lq*4+r = batch-in-group, n=lm)
#pragma unroll
        for (int r = 0; r < 4; r++)
            xch[(g * 16 + lq * 4 + r) * 16 + lm] = pre[r];
        __syncthreads();
        float pg[4];
#pragma unroll
        for (int g2 = 0; g2 < 4; g2++)
            pg[g2] = xch[(g2 * 16 + eb) * 16 + eu] + xpv[g2] + bias[g2];
        float iv = sigmoidf_(pg[0]);
        float fv = sigmoidf_(pg[1]);
        float gv = tanh_(pg[2]);
        float ov = sigmoidf_(pg[3]);
        c = fv * c + iv * gv;
        float h = ov * tanh_(c);
        float hn = __shfl_xor(h, 1);
        if ((tid & 1) == 0) {
            uint16_t lo, hi;
            {
                f16 a = (f16)h, b2 = (f16)hn;
                lo = *(uint16_t*)&a; hi = *(uint16_t*)&b2;
            }
            uint32_t pk = (uint32_t)lo | ((uint32_t)hi << 16);
            __hip_atomic_store(
                hexch + (size_t)(t & smask) * (NBATCH * 512)
                      + (size_t)batch * 512 + (hidx >> 1),
                pk, __ATOMIC_RELAXED, __HIP_MEMORY_SCOPE_AGENT);
        }
        if (dout != nullptr && t == mylen - 1)
            dout[(size_t)batch * 1024 + hidx] = h;
        __syncthreads();  // drains vmcnt(0): all waves' h stores are at the MALL
        if (tid == 0)
            __hip_atomic_store(flags + myflag, t + 1, __ATOMIC_RELAXED,
                               __HIP_MEMORY_SCOPE_AGENT);
    }
    cstate[(size_t)batch * 1024 + hidx] = c;
}

__global__ __launch_bounds__(256, 2) void lstm_dual(
    const float* __restrict__ xpA, const f16* __restrict__ WhA,
    const float* __restrict__ bsA, uint32_t* __restrict__ hxA,
    int* __restrict__ flagsA, float* __restrict__ cstA, int t0a, int smaskA,
    const float* __restrict__ xpB, const f16* __restrict__ WhB,
    const float* __restrict__ bsB, uint32_t* __restrict__ hxB,
    int* __restrict__ flagsB, float* __restrict__ cstB, int t0b,
    const int* __restrict__ lengths, float* __restrict__ dout, int nsteps) {
    __shared__ f16 hbuf[16 * 1032];
    __shared__ float xch[4 * 16 * 16];
    const int cid = blockIdx.x;
    if (cid < 256) {
        if (t0a < 0) return;           // uniform per block, before any barrier
        chain_loop(xpA, WhA, bsA, hxA, flagsA, cstA, t0a, smaskA,
                   nullptr, nullptr, cid, nsteps, hbuf, xch);
    } else {
        if (t0b < 0) return;
        chain_loop(xpB, WhB, bsB, hxB, flagsB, cstB, t0b, 1,
                   lengths, dout, cid - 256, nsteps, hbuf, xch);
    }
}

extern "C" void kernel_launch(void* const* d_in, const int* in_sizes, int n_in,
                              void* d_out, int out_size, void* d_ws, size_t ws_size,
                              hipStream_t stream) {
    const int*   x     = (const int*)d_in[0];
    const int*   len   = (const int*)d_in[1];
    const float* emb   = (const float*)d_in[2];
    const float* W_ih0 = (const float*)d_in[3];
    const float* b_ih0 = (const float*)d_in[4];
    const float* A_ih0 = (const float*)d_in[5];
    const float* B_ih0 = (const float*)d_in[6];
    const float* W_hh0 = (const float*)d_in[7];
    const float* b_hh0 = (const float*)d_in[8];
    const float* A_hh0 = (const float*)d_in[9];
    const float* B_hh0 = (const float*)d_in[10];
    const float* W_ih1 = (const float*)d_in[11];
    const float* b_ih1 = (const float*)d_in[12];
    const float* A_ih1 = (const float*)d_in[13];
    const float* B_ih1 = (const float*)d_in[14];
    const float* W_hh1 = (const float*)d_in[15];
    const float* b_hh1 = (const float*)d_in[16];
    const float* A_hh1 = (const float*)d_in[17];
    const float* B_hh1 = (const float*)d_in[18];

    char* ws = (char*)d_ws;
    size_t off = 0;
    auto alloc = [&](size_t bytes) {
        size_t o = off;
        off += (bytes + 255) & ~(size_t)255;
        return o;
    };
    f16*   W0f    = (f16*)(ws + alloc((size_t)4096 * 512 * 2));
    f16*   Wh0f   = (f16*)(ws + alloc((size_t)4096 * 1024 * 2));
    f16*   W1f    = (f16*)(ws + alloc((size_t)4096 * 1024 * 2));
    f16*   Wh1f   = (f16*)(ws + alloc((size_t)4096 * 1024 * 2));
    float* bsum0  = (float*)(ws + alloc(4096 * 4));
    float* bsum1  = (float*)(ws + alloc(4096 * 4));
    int*   flags0 = (int*)(ws + alloc(4096));
    int*   flags1 = (int*)(ws + alloc(4096));
    float* c0st   = (float*)(ws + alloc((size_t)64 * 1024 * 4));
    float* c1st   = (float*)(ws + alloc((size_t)64 * 1024 * 4));
    f16*   hx1    = (f16*)(ws + alloc((size_t)2 * 64 * 1024 * 2));

    // runtime chunk length: prefer 64 (fewer dispatches), fall back to 32
    // if the workspace can't hold two CH*64*4096 f32 xp buffers.
    int CHv = 64;
    {
        auto al = [](size_t b) { return (b + 255) & ~(size_t)255; };
        size_t need = off
            + al((size_t)64 * 64 * 512 * 2)        // seqc
            + al((size_t)64 * 64 * 1024 * 2)       // h0 ring
            + 2 * al((size_t)64 * 64 * 4096 * 4);  // xp0c, xp1c
        if (ws_size < need) CHv = 32;
    }
    const int NCHv = 512 / CHv;
    f16*   seqc = (f16*)(ws + alloc((size_t)CHv * 64 * 512 * 2));
    f16*   h0c  = (f16*)(ws + alloc((size_t)CHv * 64 * 1024 * 2));
    float* xp0c = (float*)(ws + alloc((size_t)CHv * 64 * 4096 * 4));
    float* xp1c = (float*)(ws + alloc((size_t)CHv * 64 * 4096 * 4));
    const int mtiles  = (CHv * 64) / 128;       // 32 or 16
    const int mtmask  = mtiles - 1;
    const int mtshift = (CHv == 64) ? 5 : 4;
    (void)in_sizes; (void)n_in; (void)out_size;

    fold_lora<<<1024, 256, 0, stream>>>(W_ih0, B_ih0, A_ih0, W0f, 512);
    fold_lora<<<2048, 256, 0, stream>>>(W_hh0, B_hh0, A_hh0, Wh0f, 1024);
    fold_lora<<<2048, 256, 0, stream>>>(W_ih1, B_ih1, A_ih1, W1f, 1024);
    fold_lora<<<2048, 256, 0, stream>>>(W_hh1, B_hh1, A_hh1, Wh1f, 1024);
    init_misc<<<256, 256, 0, stream>>>(b_ih0, b_hh0, b_ih1, b_hh1,
                                       bsum0, bsum1, flags0, flags1, c0st, c1st);

    // Dispatch-level software pipeline: lstm_dual(c) runs layer-0 chunk c
    // (blocks 0..255) and layer-1 chunk c-1 (blocks 256..511) concurrently;
    // gemm1(c-1) consumes h0c (written by dual(c-1)) before dual(c)
    // overwrites it (stream order).
    for (int c = 0; c <= NCHv; c++) {
        if (c < NCHv) {
            embed_gather<<<CHv, 256, 0, stream>>>(x, emb, seqc, c * CHv);
            gemm_nt<<<mtiles * 32, 256, 0, stream>>>(seqc, W0f, xp0c, 512,
                                                     mtmask, mtshift);
        }
        if (c > 0)
            gemm_nt<<<mtiles * 32, 256, 0, stream>>>(h0c, W1f, xp1c, 1024,
                                                     mtmask, mtshift);
        lstm_dual<<<512, 256, 0, stream>>>(
            xp0c, Wh0f, bsum0, (uint32_t*)h0c, flags0, c0st,
            (c < NCHv) ? c * CHv : -1, CHv - 1,
            xp1c, Wh1f, bsum1, (uint32_t*)hx1, flags1, c1st,
            (c > 0) ? (c - 1) * CHv : -1,
            len, (float*)d_out, CHv);
    }
}